// Round 1
// baseline (515.216 us; speedup 1.0000x reference)
//
#include <hip/hip_runtime.h>
#include <hip/hip_bf16.h>

// Problem constants (fixed by setup_inputs)
#define BATCH 16
#define NHEAD 16
#define DHEAD 128
#define BLK   16
#define MAXB  128
#define MAXS  (MAXB * BLK)   // 2048
#define NSPLIT 8
#define CHUNK  (MAXS / NSPLIT)  // 256
#define SCALE  0.0883883476483184f  // 1/sqrt(128)

// ws layout: [0, B*H*D) floats = rotated Q
//            then partials: per (b,h,split): D accs + m + l  (D+2 floats)
#define WSQ_FLOATS (BATCH * NHEAD * DHEAD)
#define PART_STRIDE (DHEAD + 2)

// ---------------- Kernel 1: RoPE Q/K + scatter K,V into caches ---------------
__global__ void rope_scatter(const float* __restrict__ Q,
                             const float* __restrict__ K,
                             const float* __restrict__ V,
                             float* __restrict__ Kcache,
                             float* __restrict__ Vcache,
                             const float* __restrict__ cosb,
                             const float* __restrict__ sinb,
                             const int* __restrict__ save_slots,
                             float* __restrict__ ws_q) {
    const int bh = blockIdx.x;          // b*NHEAD + h
    const int b  = bh / NHEAD;
    const int h  = bh % NHEAD;
    const int d  = threadIdx.x;         // 0..127

    const float c = cosb[b * DHEAD + d];
    const float s = sinb[b * DHEAD + d];

    const size_t qidx = (size_t)bh * DHEAD + d;
    const float qv = Q[qidx];
    const float qrot = (d < DHEAD / 2) ? -Q[qidx + DHEAD / 2] : Q[qidx - DHEAD / 2];
    ws_q[qidx] = qv * c + qrot * s;

    const float kv = K[qidx];
    const float krot = (d < DHEAD / 2) ? -K[qidx + DHEAD / 2] : K[qidx - DHEAD / 2];
    const float kr = kv * c + krot * s;

    const int slot = save_slots[b];
    const size_t cidx = (size_t)slot * (NHEAD * DHEAD) + (size_t)h * DHEAD + d;
    Kcache[cidx] = kr;
    Vcache[cidx] = V[qidx];
}

// ---------------- Kernel 2: flash-decode partial over a 256-pos chunk --------
__global__ __launch_bounds__(256) void attn_partial(
        const float* __restrict__ Kcache,
        const float* __restrict__ Vcache,
        const float* __restrict__ mask,
        const int* __restrict__ input_length,
        const int* __restrict__ block_tables,
        const float* __restrict__ ws_q,
        float* __restrict__ ws_part) {
    const int split = blockIdx.x;
    const int h     = blockIdx.y;
    const int b     = blockIdx.z;
    const int tid   = threadIdx.x;
    const int wave  = tid >> 6;
    const int lane  = tid & 63;

    float* part = ws_part + ((size_t)((b * NHEAD + h) * NSPLIT + split)) * PART_STRIDE;

    const int L  = input_length[b];
    const int s0 = split * CHUNK;
    if (s0 >= L) {
        if (tid < DHEAD) part[tid] = 0.0f;
        if (tid == 0) { part[DHEAD] = -1e30f; part[DHEAD + 1] = 0.0f; }
        return;
    }
    const int n = min(CHUNK, L - s0);

    // per-lane fragment of rotated q (2 consecutive floats)
    const float2 q = ((const float2*)(ws_q + (size_t)(b * NHEAD + h) * DHEAD))[lane];

    float m = -1e30f, l = 0.0f;
    float2 acc = make_float2(0.0f, 0.0f);

    for (int i = wave; i < n; i += 4) {
        const int s = s0 + i;
        const int slot = block_tables[b * MAXB + (s >> 4)] * BLK + (s & (BLK - 1));
        const size_t base = (size_t)slot * (NHEAD * DHEAD) + (size_t)h * DHEAD;
        // issue both loads before any use — two independent VMEM ops in flight
        const float2 k = ((const float2*)(Kcache + base))[lane];
        const float2 v = ((const float2*)(Vcache + base))[lane];

        float dot = k.x * q.x + k.y * q.y;
        #pragma unroll
        for (int off = 32; off >= 1; off >>= 1)
            dot += __shfl_xor(dot, off, 64);

        const float score = dot * SCALE + mask[(size_t)b * MAXS + s];
        const float mn    = fmaxf(m, score);
        const float p     = __expf(score - mn);
        const float alpha = __expf(m - mn);
        l = l * alpha + p;
        acc.x = acc.x * alpha + p * v.x;
        acc.y = acc.y * alpha + p * v.y;
        m = mn;
    }

    // combine the 4 waves via LDS
    __shared__ float sm[4], sl[4];
    __shared__ float sacc[4][DHEAD];
    sacc[wave][2 * lane]     = acc.x;
    sacc[wave][2 * lane + 1] = acc.y;
    if (lane == 0) { sm[wave] = m; sl[wave] = l; }
    __syncthreads();

    if (tid < DHEAD) {
        float M = fmaxf(fmaxf(sm[0], sm[1]), fmaxf(sm[2], sm[3]));
        float a = 0.0f;
        #pragma unroll
        for (int w = 0; w < 4; ++w) a += sacc[w][tid] * __expf(sm[w] - M);
        part[tid] = a;
        if (tid == 0) {
            float lt = 0.0f;
            #pragma unroll
            for (int w = 0; w < 4; ++w) lt += sl[w] * __expf(sm[w] - M);
            part[DHEAD] = M;
            part[DHEAD + 1] = lt;
        }
    }
}

// ---------------- Kernel 3: combine NSPLIT partials -> out -------------------
__global__ void attn_combine(const float* __restrict__ ws_part,
                             float* __restrict__ out) {
    const int bh = blockIdx.x;
    const int d  = threadIdx.x;  // 0..127

    const float* base = ws_part + (size_t)bh * NSPLIT * PART_STRIDE;

    float M = -1e30f;
    #pragma unroll
    for (int s = 0; s < NSPLIT; ++s)
        M = fmaxf(M, base[s * PART_STRIDE + DHEAD]);

    float lsum = 0.0f, a = 0.0f;
    #pragma unroll
    for (int s = 0; s < NSPLIT; ++s) {
        const float f = __expf(base[s * PART_STRIDE + DHEAD] - M);
        lsum += base[s * PART_STRIDE + DHEAD + 1] * f;
        a    += base[s * PART_STRIDE + d] * f;
    }
    out[(size_t)bh * DHEAD + d] = a / lsum;
}

extern "C" void kernel_launch(void* const* d_in, const int* in_sizes, int n_in,
                              void* d_out, int out_size, void* d_ws, size_t ws_size,
                              hipStream_t stream) {
    const float* Q       = (const float*)d_in[0];
    const float* K       = (const float*)d_in[1];
    const float* V       = (const float*)d_in[2];
    float*       Kcache  = (float*)d_in[3];   // harness restores inputs each launch
    float*       Vcache  = (float*)d_in[4];
    const float* cosb    = (const float*)d_in[5];
    const float* sinb    = (const float*)d_in[6];
    const float* mask    = (const float*)d_in[7];
    const int*   in_len  = (const int*)d_in[8];
    const int*   slots   = (const int*)d_in[9];
    const int*   btab    = (const int*)d_in[10];
    // d_in[11] = max_s scalar, compile-time constant here

    float* ws_q    = (float*)d_ws;
    float* ws_part = ws_q + WSQ_FLOATS;
    float* out     = (float*)d_out;

    rope_scatter<<<BATCH * NHEAD, DHEAD, 0, stream>>>(
        Q, K, V, Kcache, Vcache, cosb, sinb, slots, ws_q);

    dim3 grid2(NSPLIT, NHEAD, BATCH);
    attn_partial<<<grid2, 256, 0, stream>>>(
        Kcache, Vcache, mask, in_len, btab, ws_q, ws_part);

    attn_combine<<<BATCH * NHEAD, DHEAD, 0, stream>>>(ws_part, out);
}

// Round 2
// 492.569 us; speedup vs baseline: 1.0460x; 1.0460x over previous
//
#include <hip/hip_runtime.h>
#include <hip/hip_bf16.h>

// Problem constants (fixed by setup_inputs)
#define BATCH 16
#define NHEAD 16
#define DHEAD 128
#define BLK   16
#define MAXB  128
#define MAXS  (MAXB * BLK)   // 2048
#define NSPLIT 8
#define CHUNK  (MAXS / NSPLIT)  // 256
#define SCALE  0.0883883476483184f  // 1/sqrt(128)

// ws layout: [0, B*H*D) floats = rotated Q
//            then partials: per (b,h,split): D accs + m + l  (D+2 floats)
#define WSQ_FLOATS (BATCH * NHEAD * DHEAD)
#define PART_STRIDE (DHEAD + 2)

// ---------------- Kernel 1: RoPE Q/K + scatter K,V into caches ---------------
__global__ void rope_scatter(const float* __restrict__ Q,
                             const float* __restrict__ K,
                             const float* __restrict__ V,
                             float* __restrict__ Kcache,
                             float* __restrict__ Vcache,
                             const float* __restrict__ cosb,
                             const float* __restrict__ sinb,
                             const int* __restrict__ save_slots,
                             float* __restrict__ ws_q) {
    const int bh = blockIdx.x;          // b*NHEAD + h
    const int b  = bh / NHEAD;
    const int h  = bh % NHEAD;
    const int d  = threadIdx.x;         // 0..127

    const float c = cosb[b * DHEAD + d];
    const float s = sinb[b * DHEAD + d];

    const size_t qidx = (size_t)bh * DHEAD + d;
    const float qv = Q[qidx];
    const float qrot = (d < DHEAD / 2) ? -Q[qidx + DHEAD / 2] : Q[qidx - DHEAD / 2];
    ws_q[qidx] = qv * c + qrot * s;

    const float kv = K[qidx];
    const float krot = (d < DHEAD / 2) ? -K[qidx + DHEAD / 2] : K[qidx - DHEAD / 2];
    const float kr = kv * c + krot * s;

    const int slot = save_slots[b];
    const size_t cidx = (size_t)slot * (NHEAD * DHEAD) + (size_t)h * DHEAD + d;
    Kcache[cidx] = kr;
    Vcache[cidx] = V[qidx];
}

// ---------------- Kernel 2: flash-decode partial over a 256-pos chunk --------
// 256 threads = 8 independent 32-lane softmax units. Each unit owns positions
// strided by 8; lane holds float4 of D=128 (32 lanes x 4 = 128). Reduction is
// a 5-step butterfly within 32 lanes (xor offsets <32 stay in the half-wave).
// 2 positions per unit-iteration -> 4 independent 16B/lane loads in flight,
// one alpha-exp per pair.
__global__ __launch_bounds__(256) void attn_partial(
        const float* __restrict__ Kcache,
        const float* __restrict__ Vcache,
        const float* __restrict__ mask,
        const int* __restrict__ input_length,
        const int* __restrict__ block_tables,
        const float* __restrict__ ws_q,
        float* __restrict__ ws_part) {
    const int split = blockIdx.x;
    const int h     = blockIdx.y;
    const int b     = blockIdx.z;
    const int tid   = threadIdx.x;
    const int hw    = tid >> 5;   // 0..7: softmax unit
    const int ln    = tid & 31;   // lane within unit

    float* part = ws_part + ((size_t)((b * NHEAD + h) * NSPLIT + split)) * PART_STRIDE;

    const int L  = input_length[b];
    const int s0 = split * CHUNK;
    if (s0 >= L) {
        if (tid < DHEAD) part[tid] = 0.0f;
        if (tid == 0) { part[DHEAD] = -1e30f; part[DHEAD + 1] = 0.0f; }
        return;
    }
    const int n = min(CHUNK, L - s0);

    const float4 q = ((const float4*)(ws_q + (size_t)(b * NHEAD + h) * DHEAD))[ln];
    const float* mrow = mask + (size_t)b * MAXS + s0;
    const int*   bt   = block_tables + b * MAXB;

    float m = -1e30f, l = 0.0f;
    float4 acc = make_float4(0.0f, 0.0f, 0.0f, 0.0f);

    int i = hw;
    // pair loop: positions i and i+8
    for (; i + 8 < n; i += 16) {
        const int sA = s0 + i;
        const int sB = sA + 8;
        const size_t baseA = (size_t)(bt[sA >> 4] * BLK + (sA & (BLK - 1))) * (NHEAD * DHEAD)
                           + (size_t)h * DHEAD;
        const size_t baseB = (size_t)(bt[sB >> 4] * BLK + (sB & (BLK - 1))) * (NHEAD * DHEAD)
                           + (size_t)h * DHEAD;
        // 4 independent loads issued before any use
        const float4 kA = ((const float4*)(Kcache + baseA))[ln];
        const float4 kB = ((const float4*)(Kcache + baseB))[ln];
        const float4 vA = ((const float4*)(Vcache + baseA))[ln];
        const float4 vB = ((const float4*)(Vcache + baseB))[ln];

        float dA = kA.x * q.x + kA.y * q.y + kA.z * q.z + kA.w * q.w;
        float dB = kB.x * q.x + kB.y * q.y + kB.z * q.z + kB.w * q.w;
        #pragma unroll
        for (int off = 16; off >= 1; off >>= 1) {
            dA += __shfl_xor(dA, off, 64);
            dB += __shfl_xor(dB, off, 64);
        }

        const float scA = dA * SCALE + mrow[i];
        const float scB = dB * SCALE + mrow[i + 8];
        const float mn  = fmaxf(m, fmaxf(scA, scB));
        const float pA  = __expf(scA - mn);
        const float pB  = __expf(scB - mn);
        const float al  = __expf(m - mn);
        l = l * al + pA + pB;
        acc.x = acc.x * al + pA * vA.x + pB * vB.x;
        acc.y = acc.y * al + pA * vA.y + pB * vB.y;
        acc.z = acc.z * al + pA * vA.z + pB * vB.z;
        acc.w = acc.w * al + pA * vA.w + pB * vB.w;
        m = mn;
    }
    // tail: at most one position left for this unit
    if (i < n) {
        const int s = s0 + i;
        const size_t base = (size_t)(bt[s >> 4] * BLK + (s & (BLK - 1))) * (NHEAD * DHEAD)
                          + (size_t)h * DHEAD;
        const float4 k = ((const float4*)(Kcache + base))[ln];
        const float4 v = ((const float4*)(Vcache + base))[ln];
        float d = k.x * q.x + k.y * q.y + k.z * q.z + k.w * q.w;
        #pragma unroll
        for (int off = 16; off >= 1; off >>= 1) d += __shfl_xor(d, off, 64);
        const float sc = d * SCALE + mrow[i];
        const float mn = fmaxf(m, sc);
        const float p  = __expf(sc - mn);
        const float al = __expf(m - mn);
        l = l * al + p;
        acc.x = acc.x * al + p * v.x;
        acc.y = acc.y * al + p * v.y;
        acc.z = acc.z * al + p * v.z;
        acc.w = acc.w * al + p * v.w;
        m = mn;
    }

    // merge the 8 units via LDS
    __shared__ float sm[8], sl[8];
    __shared__ float sacc[8][DHEAD];
    ((float4*)sacc[hw])[ln] = acc;
    if (ln == 0) { sm[hw] = m; sl[hw] = l; }
    __syncthreads();

    if (tid < DHEAD) {
        float M = -1e30f;
        #pragma unroll
        for (int w = 0; w < 8; ++w) M = fmaxf(M, sm[w]);
        float a = 0.0f;
        #pragma unroll
        for (int w = 0; w < 8; ++w) a += sacc[w][tid] * __expf(sm[w] - M);
        part[tid] = a;
        if (tid == 0) {
            float lt = 0.0f;
            #pragma unroll
            for (int w = 0; w < 8; ++w) lt += sl[w] * __expf(sm[w] - M);
            part[DHEAD] = M;
            part[DHEAD + 1] = lt;
        }
    }
}

// ---------------- Kernel 3: combine NSPLIT partials -> out -------------------
__global__ void attn_combine(const float* __restrict__ ws_part,
                             float* __restrict__ out) {
    const int bh = blockIdx.x;
    const int d  = threadIdx.x;  // 0..127

    const float* base = ws_part + (size_t)bh * NSPLIT * PART_STRIDE;

    float M = -1e30f;
    #pragma unroll
    for (int s = 0; s < NSPLIT; ++s)
        M = fmaxf(M, base[s * PART_STRIDE + DHEAD]);

    float lsum = 0.0f, a = 0.0f;
    #pragma unroll
    for (int s = 0; s < NSPLIT; ++s) {
        const float f = __expf(base[s * PART_STRIDE + DHEAD] - M);
        lsum += base[s * PART_STRIDE + DHEAD + 1] * f;
        a    += base[s * PART_STRIDE + d] * f;
    }
    out[(size_t)bh * DHEAD + d] = a / lsum;
}

extern "C" void kernel_launch(void* const* d_in, const int* in_sizes, int n_in,
                              void* d_out, int out_size, void* d_ws, size_t ws_size,
                              hipStream_t stream) {
    const float* Q       = (const float*)d_in[0];
    const float* K       = (const float*)d_in[1];
    const float* V       = (const float*)d_in[2];
    float*       Kcache  = (float*)d_in[3];   // harness restores inputs each launch
    float*       Vcache  = (float*)d_in[4];
    const float* cosb    = (const float*)d_in[5];
    const float* sinb    = (const float*)d_in[6];
    const float* mask    = (const float*)d_in[7];
    const int*   in_len  = (const int*)d_in[8];
    const int*   slots   = (const int*)d_in[9];
    const int*   btab    = (const int*)d_in[10];
    // d_in[11] = max_s scalar, compile-time constant here

    float* ws_q    = (float*)d_ws;
    float* ws_part = ws_q + WSQ_FLOATS;
    float* out     = (float*)d_out;

    rope_scatter<<<BATCH * NHEAD, DHEAD, 0, stream>>>(
        Q, K, V, Kcache, Vcache, cosb, sinb, slots, ws_q);

    dim3 grid2(NSPLIT, NHEAD, BATCH);
    attn_partial<<<grid2, 256, 0, stream>>>(
        Kcache, Vcache, mask, in_len, btab, ws_q, ws_part);

    attn_combine<<<BATCH * NHEAD, DHEAD, 0, stream>>>(ws_part, out);
}

// Round 3
// 472.343 us; speedup vs baseline: 1.0908x; 1.0428x over previous
//
#include <hip/hip_runtime.h>
#include <hip/hip_bf16.h>

// Problem constants (fixed by setup_inputs)
#define BATCH 16
#define NHEAD 16
#define DHEAD 128
#define BLK   16
#define MAXB  128
#define MAXS  (MAXB * BLK)   // 2048
#define NSPLIT 8
#define CHUNK  (MAXS / NSPLIT)  // 256 == blockDim
#define SCALE  0.0883883476483184f  // 1/sqrt(128)

// ws layout: [0, B*H*D) floats = rotated Q
//            then partials: per (b,h,split): D accs + m + l  (D+2 floats)
#define WSQ_FLOATS (BATCH * NHEAD * DHEAD)
#define PART_STRIDE (DHEAD + 2)

// ---------------- Kernel 1: RoPE Q/K + scatter K,V into caches ---------------
__global__ void rope_scatter(const float* __restrict__ Q,
                             const float* __restrict__ K,
                             const float* __restrict__ V,
                             float* __restrict__ Kcache,
                             float* __restrict__ Vcache,
                             const float* __restrict__ cosb,
                             const float* __restrict__ sinb,
                             const int* __restrict__ save_slots,
                             float* __restrict__ ws_q) {
    const int bh = blockIdx.x;          // b*NHEAD + h
    const int b  = bh / NHEAD;
    const int h  = bh % NHEAD;
    const int d  = threadIdx.x;         // 0..127

    const float c = cosb[b * DHEAD + d];
    const float s = sinb[b * DHEAD + d];

    const size_t qidx = (size_t)bh * DHEAD + d;
    const float qv = Q[qidx];
    const float qrot = (d < DHEAD / 2) ? -Q[qidx + DHEAD / 2] : Q[qidx - DHEAD / 2];
    ws_q[qidx] = qv * c + qrot * s;

    const float kv = K[qidx];
    const float krot = (d < DHEAD / 2) ? -K[qidx + DHEAD / 2] : K[qidx - DHEAD / 2];
    const float kr = kv * c + krot * s;

    const int slot = save_slots[b];
    const size_t cidx = (size_t)slot * (NHEAD * DHEAD) + (size_t)h * DHEAD + d;
    Kcache[cidx] = kr;
    Vcache[cidx] = V[qidx];
}

// ---------------- Kernel 2: chain-free flash-decode partial ------------------
// Phases: (0) precompute 256 per-position base offsets into LDS;
// (1) K-pass: streaming dot products -> raw scores in LDS (no serial chain);
// (2) block softmax over <=256 scores; (3) V-pass: streaming weighted sum,
// no rescaling (shared block max). 8 units of 32 lanes; lane holds float4.
__global__ __launch_bounds__(256) void attn_partial(
        const float* __restrict__ Kcache,
        const float* __restrict__ Vcache,
        const float* __restrict__ mask,
        const int* __restrict__ input_length,
        const int* __restrict__ block_tables,
        const float* __restrict__ ws_q,
        float* __restrict__ ws_part) {
    const int split = blockIdx.x;
    const int h     = blockIdx.y;
    const int b     = blockIdx.z;
    const int tid   = threadIdx.x;
    const int hw    = tid >> 5;   // 0..7: softmax unit
    const int ln    = tid & 31;   // lane within unit

    __shared__ int   sbase[CHUNK];        // per-position float index into caches
    __shared__ float sp[CHUNK];           // raw scores, then probabilities
    __shared__ float sred[8];             // [0..3] wave maxes, [4..7] wave sums
    __shared__ float sacc[8][DHEAD];      // per-unit accumulators

    float* part = ws_part + ((size_t)((b * NHEAD + h) * NSPLIT + split)) * PART_STRIDE;

    const int L  = input_length[b];
    const int s0 = split * CHUNK;
    if (s0 >= L) {
        if (tid < DHEAD) part[tid] = 0.0f;
        if (tid == 0) { part[DHEAD] = -1e30f; part[DHEAD + 1] = 0.0f; }
        return;
    }
    const int n = min(CHUNK, L - s0);

    // ---- phase 0: base offsets (one thread per position) ----
    if (tid < n) {
        const int s = s0 + tid;
        sbase[tid] = block_tables[b * MAXB + (s >> 4)] * (BLK * NHEAD * DHEAD)
                   + (s & (BLK - 1)) * (NHEAD * DHEAD) + h * DHEAD;
    }
    const float4 q = ((const float4*)(ws_q + (size_t)(b * NHEAD + h) * DHEAD))[ln];
    __syncthreads();

    // ---- phase 1: K-pass, raw dot products (fully pipelineable) ----
    #pragma unroll 4
    for (int i = hw; i < n; i += 8) {
        const float4 k = ((const float4*)(Kcache + sbase[i]))[ln];
        float d = k.x * q.x + k.y * q.y + k.z * q.z + k.w * q.w;
        #pragma unroll
        for (int off = 16; off >= 1; off >>= 1)
            d += __shfl_xor(d, off, 64);
        if (ln == 0) sp[i] = d;
    }
    __syncthreads();

    // ---- phase 2: block softmax over sp[0..n) ----
    const float sc = (tid < n) ? sp[tid] * SCALE + mask[(size_t)b * MAXS + s0 + tid]
                               : -1e30f;
    float wm = sc;
    #pragma unroll
    for (int off = 32; off >= 1; off >>= 1)
        wm = fmaxf(wm, __shfl_xor(wm, off, 64));
    if ((tid & 63) == 0) sred[tid >> 6] = wm;
    __syncthreads();
    const float M = fmaxf(fmaxf(sred[0], sred[1]), fmaxf(sred[2], sred[3]));
    const float p = (tid < n) ? __expf(sc - M) : 0.0f;
    sp[tid] = p;                       // safe: own slot, everyone past sync
    float wsum = p;
    #pragma unroll
    for (int off = 32; off >= 1; off >>= 1)
        wsum += __shfl_xor(wsum, off, 64);
    if ((tid & 63) == 0) sred[4 + (tid >> 6)] = wsum;
    __syncthreads();
    const float l = (sred[4] + sred[5]) + (sred[6] + sred[7]);

    // ---- phase 3: V-pass, streaming weighted accumulation ----
    float4 acc = make_float4(0.0f, 0.0f, 0.0f, 0.0f);
    #pragma unroll 4
    for (int i = hw; i < n; i += 8) {
        const float4 v = ((const float4*)(Vcache + sbase[i]))[ln];
        const float pi = sp[i];
        acc.x += pi * v.x;
        acc.y += pi * v.y;
        acc.z += pi * v.z;
        acc.w += pi * v.w;
    }

    // ---- merge 8 units (same M -> plain sum) ----
    ((float4*)sacc[hw])[ln] = acc;
    __syncthreads();
    if (tid < DHEAD) {
        float a = 0.0f;
        #pragma unroll
        for (int w = 0; w < 8; ++w) a += sacc[w][tid];
        part[tid] = a;
        if (tid == 0) { part[DHEAD] = M; part[DHEAD + 1] = l; }
    }
}

// ---------------- Kernel 3: combine NSPLIT partials -> out -------------------
__global__ void attn_combine(const float* __restrict__ ws_part,
                             float* __restrict__ out) {
    const int bh = blockIdx.x;
    const int d  = threadIdx.x;  // 0..127

    const float* base = ws_part + (size_t)bh * NSPLIT * PART_STRIDE;

    float M = -1e30f;
    #pragma unroll
    for (int s = 0; s < NSPLIT; ++s)
        M = fmaxf(M, base[s * PART_STRIDE + DHEAD]);

    float lsum = 0.0f, a = 0.0f;
    #pragma unroll
    for (int s = 0; s < NSPLIT; ++s) {
        const float f = __expf(base[s * PART_STRIDE + DHEAD] - M);
        lsum += base[s * PART_STRIDE + DHEAD + 1] * f;
        a    += base[s * PART_STRIDE + d] * f;
    }
    out[(size_t)bh * DHEAD + d] = a / lsum;
}

extern "C" void kernel_launch(void* const* d_in, const int* in_sizes, int n_in,
                              void* d_out, int out_size, void* d_ws, size_t ws_size,
                              hipStream_t stream) {
    const float* Q       = (const float*)d_in[0];
    const float* K       = (const float*)d_in[1];
    const float* V       = (const float*)d_in[2];
    float*       Kcache  = (float*)d_in[3];   // harness restores inputs each launch
    float*       Vcache  = (float*)d_in[4];
    const float* cosb    = (const float*)d_in[5];
    const float* sinb    = (const float*)d_in[6];
    const float* mask    = (const float*)d_in[7];
    const int*   in_len  = (const int*)d_in[8];
    const int*   slots   = (const int*)d_in[9];
    const int*   btab    = (const int*)d_in[10];
    // d_in[11] = max_s scalar, compile-time constant here

    float* ws_q    = (float*)d_ws;
    float* ws_part = ws_q + WSQ_FLOATS;
    float* out     = (float*)d_out;

    rope_scatter<<<BATCH * NHEAD, DHEAD, 0, stream>>>(
        Q, K, V, Kcache, Vcache, cosb, sinb, slots, ws_q);

    dim3 grid2(NSPLIT, NHEAD, BATCH);
    attn_partial<<<grid2, 256, 0, stream>>>(
        Kcache, Vcache, mask, in_len, btab, ws_q, ws_part);

    attn_combine<<<BATCH * NHEAD, DHEAD, 0, stream>>>(ws_part, out);
}